// Round 5
// baseline (216.550 us; speedup 1.0000x reference)
//
#include <hip/hip_runtime.h>

// NeuralRodriguesOperator: B=512, C_L=64, C_J=16, 4x4 matrices.
// R5: MFMA reformulation. R4 counters proved the fp32 path is LDS-return-BW
// bound (broadcast ds_read_b128 still costs 1 KiB/inst of return bandwidth;
// model 109 us vs measured 122 us). Only the matrix unit amortizes operand
// delivery across rows. Reformulate as two bf16 GEMMs, K=8448:
//   trig[b,c'] = (1, cos th, sin th),  k = c'*256 + i*4 + q
//   A1[(b,p),k] = trig[b,c']*F[b,i,p,q]   B1t[(j,r),k] = Wcat [j,i,c',q,r]
//   A2[(b,r),k] = trig[b,c']*F[b,i,q,r]   B2t[(j,p),k] = Wbcat[j,i,c',p,q]
//   out[b,j,p,r] = C1[(b,p),(j,r)] + C2[(b,r),(j,p)]
// GEMM: m97 structure (128x128 tile, BK=32, global_load_lds width 16,
// 16x16x32 bf16 MFMA), split-K=8 -> 512 blocks; epilogue atomicAdds fp32
// into permuted out (memset-zeroed). ws: A1,A2,B1t,B2t bf16 = 77.9 MB.

#define NRO_B   512
#define NRO_CL  64
#define NRO_CJ  16
#define K_DIM   8448          // 33 * 256
#define M_DIM   2048
#define N_DIM   256
#define A_ELems ((size_t)M_DIM * K_DIM)     // per matrix
#define B_ELems ((size_t)N_DIM * K_DIM)

typedef __attribute__((ext_vector_type(8))) short short8;
typedef __attribute__((ext_vector_type(4))) float floatx4;

__device__ __forceinline__ short f2bf(float x) {
    union { float f; unsigned u; } a; a.f = x;
    unsigned r = a.u + 0x7FFF + ((a.u >> 16) & 1);   // RNE
    return (short)(r >> 16);
}

__device__ __forceinline__ void load16(const float* p, float w[4][4]) {
    const float4* p4 = (const float4*)p;
    #pragma unroll
    for (int a = 0; a < 4; ++a) {
        float4 x = p4[a];
        w[a][0] = x.x; w[a][1] = x.y; w[a][2] = x.z; w[a][3] = x.w;
    }
}

// ---------------- prep A: one wave per (mat, b) ----------------
__global__ __launch_bounds__(256) void nro_prep_a(
    const float* __restrict__ F_in, const float* __restrict__ theta,
    short* __restrict__ Abuf)                 // [2][2048][8448] bf16
{
    const int unit = blockIdx.x * 4 + (threadIdx.x >> 6);  // 0..1023
    const int mat  = unit >> 9;                            // 0/1
    const int b    = unit & 511;
    const int i    = threadIdx.x & 63;                     // lane = i

    float f[4][4];
    load16(F_in + ((size_t)b * 64 + i) * 16, f);           // f[p][q]

    float tc[33];
    tc[0] = 1.0f;
    #pragma unroll
    for (int c = 0; c < 16; ++c) {
        float th = theta[b * 16 + c];
        tc[1 + c]  = __cosf(th);
        tc[17 + c] = __sinf(th);
    }

    // mat0 row a=p: rv[a][q] = F[b,i,p=a,q];  mat1 row a=r: rv[a][q] = F[b,i,q,a]
    float rv[4][4];
    #pragma unroll
    for (int a = 0; a < 4; ++a)
        #pragma unroll
        for (int q = 0; q < 4; ++q)
            rv[a][q] = (mat == 0) ? f[a][q] : f[q][a];

    #pragma unroll
    for (int a = 0; a < 4; ++a) {
        short* rowp = Abuf + ((size_t)mat * M_DIM + b * 4 + a) * K_DIM + i * 4;
        #pragma unroll
        for (int cp = 0; cp < 33; ++cp) {
            float t = tc[cp];
            short4 v;
            v.x = f2bf(rv[a][0] * t); v.y = f2bf(rv[a][1] * t);
            v.z = f2bf(rv[a][2] * t); v.w = f2bf(rv[a][3] * t);
            *(short4*)(rowp + cp * 256) = v;   // lanes i -> 8B stride, coalesced
        }
    }
}

// ---------------- prep B: one wave per (j, c) ----------------
__global__ __launch_bounds__(256) void nro_prep_b(
    const float* __restrict__ W_bias, const float* __restrict__ W_cos,
    const float* __restrict__ W_sin,  const float* __restrict__ Wb_bias,
    const float* __restrict__ Wb_cos, const float* __restrict__ Wb_sin,
    short* __restrict__ Bbuf)                 // [2][256][8448] bf16
{
    const int unit = blockIdx.x * 4 + (threadIdx.x >> 6);  // 0..1023
    const int j = unit >> 4;
    const int c = unit & 15;
    const int i = threadIdx.x & 63;

    short* B1 = Bbuf;
    short* B2 = Bbuf + B_ELems;

    const size_t wbase = (((size_t)(j * 64 + i)) * 16 + c) * 16;
    float wc[4][4], ws[4][4], wbc[4][4], wbs[4][4];      // [x][y] = [.,x,y]
    load16(W_cos  + wbase, wc);
    load16(W_sin  + wbase, ws);
    load16(Wb_cos + wbase, wbc);
    load16(Wb_sin + wbase, wbs);

    // B1t[(j,r)][(1+c)*256 + i*4 + q] = W_cos[j,i,c,q,r]  (transpose q<->r)
    #pragma unroll
    for (int r = 0; r < 4; ++r) {
        short* n1 = B1 + (size_t)(j * 4 + r) * K_DIM + i * 4;
        short4 v;
        v.x = f2bf(wc[0][r]); v.y = f2bf(wc[1][r]); v.z = f2bf(wc[2][r]); v.w = f2bf(wc[3][r]);
        *(short4*)(n1 + (1 + c) * 256) = v;
        v.x = f2bf(ws[0][r]); v.y = f2bf(ws[1][r]); v.z = f2bf(ws[2][r]); v.w = f2bf(ws[3][r]);
        *(short4*)(n1 + (17 + c) * 256) = v;
    }
    // B2t[(j,p)][(1+c)*256 + i*4 + q] = Wb_cos[j,i,c,p,q]  (direct)
    #pragma unroll
    for (int p = 0; p < 4; ++p) {
        short* n2 = B2 + (size_t)(j * 4 + p) * K_DIM + i * 4;
        short4 v;
        v.x = f2bf(wbc[p][0]); v.y = f2bf(wbc[p][1]); v.z = f2bf(wbc[p][2]); v.w = f2bf(wbc[p][3]);
        *(short4*)(n2 + (1 + c) * 256) = v;
        v.x = f2bf(wbs[p][0]); v.y = f2bf(wbs[p][1]); v.z = f2bf(wbs[p][2]); v.w = f2bf(wbs[p][3]);
        *(short4*)(n2 + (17 + c) * 256) = v;
    }

    if (c == 0) {   // c' = 0: bias slices
        float t1[4][4], t2[4][4];
        load16(W_bias  + ((size_t)(j * 64 + i)) * 16, t1);  // [q][r]
        load16(Wb_bias + ((size_t)(j * 64 + i)) * 16, t2);  // [p][q]
        #pragma unroll
        for (int r = 0; r < 4; ++r) {
            short4 v;
            v.x = f2bf(t1[0][r]); v.y = f2bf(t1[1][r]); v.z = f2bf(t1[2][r]); v.w = f2bf(t1[3][r]);
            *(short4*)(B1 + (size_t)(j * 4 + r) * K_DIM + i * 4) = v;
        }
        #pragma unroll
        for (int p = 0; p < 4; ++p) {
            short4 v;
            v.x = f2bf(t2[p][0]); v.y = f2bf(t2[p][1]); v.z = f2bf(t2[p][2]); v.w = f2bf(t2[p][3]);
            *(short4*)(B2 + (size_t)(j * 4 + p) * K_DIM + i * 4) = v;
        }
    }
}

// ---------------- GEMM: m97 structure + permuted atomic epilogue ----------------
__global__ __launch_bounds__(256, 2) void nro_gemm(
    const short* __restrict__ Abuf, const short* __restrict__ Bbuf,
    float* __restrict__ out)                  // (B, CL, 4, 4), pre-zeroed
{
    const int tile = blockIdx.x;              // 0..31 : mt*2+nt
    const int m0   = (tile >> 1) * 128;
    const int n0   = (tile & 1) * 128;
    const int sk   = blockIdx.y;              // 0..7
    const int z    = blockIdx.z;              // 0/1 : which GEMM
    const short* A = Abuf + (size_t)z * A_ELems;
    const short* Bm = Bbuf + (size_t)z * B_ELems;
    const int kb = sk * (K_DIM / 8);          // 1056 per split

    __shared__ short As[128 * 32];
    __shared__ short Bs[128 * 32];

    const int tid  = threadIdx.x;
    const int lane = tid & 63;
    const int w    = tid >> 6;                // wave 0..3
    const int wm   = (w >> 1) * 64, wn = (w & 1) * 64;

    floatx4 acc[4][4] = {};

    const int rowl = w * 16 + (lane >> 2);    // staging row within 64-row half
    const int col8 = (lane & 3) * 8;          // k-offset (elements)

    for (int kt = 0; kt < 33; ++kt) {
        const int k0 = kb + kt * 32;
        __syncthreads();                       // prior frags consumed
        #pragma unroll
        for (int r = 0; r < 2; ++r) {
            const short* ga = A  + (size_t)(m0 + r * 64 + rowl) * K_DIM + k0 + col8;
            const short* gb = Bm + (size_t)(n0 + r * 64 + rowl) * K_DIM + k0 + col8;
            __builtin_amdgcn_global_load_lds(
                (const __attribute__((address_space(1))) void*)ga,
                (__attribute__((address_space(3))) void*)(As + (r * 64 + w * 16) * 32),
                16, 0, 0);
            __builtin_amdgcn_global_load_lds(
                (const __attribute__((address_space(1))) void*)gb,
                (__attribute__((address_space(3))) void*)(Bs + (r * 64 + w * 16) * 32),
                16, 0, 0);
        }
        __syncthreads();                       // vmcnt(0) drain + barrier

        const int fr = lane & 15;
        const int fq = (lane >> 4) * 8;        // k-chunk per quad
        short8 af[4], bf[4];
        #pragma unroll
        for (int t = 0; t < 4; ++t) {
            af[t] = *(const short8*)(As + (wm + t * 16 + fr) * 32 + fq);
            bf[t] = *(const short8*)(Bs + (wn + t * 16 + fr) * 32 + fq);
        }
        #pragma unroll
        for (int mt = 0; mt < 4; ++mt)
            #pragma unroll
            for (int nt = 0; nt < 4; ++nt)
                acc[mt][nt] = __builtin_amdgcn_mfma_f32_16x16x32_bf16(
                    af[mt], bf[nt], acc[mt][nt], 0, 0, 0);
    }

    // Epilogue: C row m=(lane>>4)*4+e, col n=lane&15 [m89/m91 verified].
    // z=0: out[b,j,p,r] += C1,  m=(b,p), n=(j,r)
    // z=1: out[b,j,p,r] += C2,  m=(b,r), n=(j,p)
    const int col  = lane & 15;
    const int row4 = (lane >> 4) * 4;
    #pragma unroll
    for (int mt = 0; mt < 4; ++mt) {
        #pragma unroll
        for (int nt = 0; nt < 4; ++nt) {
            #pragma unroll
            for (int e = 0; e < 4; ++e) {
                const int m = m0 + wm + mt * 16 + row4 + e;
                const int n = n0 + wn + nt * 16 + col;
                const int oidx = (z == 0)
                    ? ((m >> 2) * 1024 + (n >> 2) * 16 + (m & 3) * 4 + (n & 3))
                    : ((m >> 2) * 1024 + (n >> 2) * 16 + (n & 3) * 4 + (m & 3));
                atomicAdd(out + oidx, acc[mt][nt][e]);
            }
        }
    }
}

// ---------------- fallback (R4 fp32 path, atomic epilogue) ----------------
__global__ __launch_bounds__(256, 2) void nro_fallback(
    const float* __restrict__ F_in, const float* __restrict__ theta,
    const float* __restrict__ W_bias, const float* __restrict__ W_cos,
    const float* __restrict__ W_sin,  const float* __restrict__ Wb_bias,
    const float* __restrict__ Wb_cos, const float* __restrict__ Wb_sin,
    float* __restrict__ out)
{
    __shared__ float smem[8448];
    const int j      = blockIdx.x >> 3;
    const int isplit = blockIdx.x & 7;
    const int i0     = isplit * 8;
    const int lane   = threadIdx.x & 63;
    const int chunk  = __builtin_amdgcn_readfirstlane(threadIdx.x >> 6);
    const int b      = blockIdx.y * 64 + lane;
    const int tid    = threadIdx.x;
    {
        float4* s4 = (float4*)smem;
        const int base16  = (j * 64 + i0) * 16;
        const int base256 = (j * 64 + i0) * 256;
        if (tid < 32)      s4[tid] = ((const float4*)(W_bias + base16))[tid];
        else if (tid < 64) s4[tid] = ((const float4*)(Wb_bias + base16))[tid - 32];
        #pragma unroll
        for (int r = 0; r < 2; ++r) {
            const int k = r * 256 + tid;
            s4[64 + k]   = ((const float4*)(W_cos  + base256))[k];
            s4[576 + k]  = ((const float4*)(W_sin  + base256))[k];
            s4[1088 + k] = ((const float4*)(Wb_cos + base256))[k];
            s4[1600 + k] = ((const float4*)(Wb_sin + base256))[k];
        }
    }
    float csc[16], css[16];
    #pragma unroll
    for (int c = 0; c < 16; ++c) {
        float t = theta[b * 16 + c];
        csc[c] = __cosf(t); css[c] = __sinf(t);
    }
    __syncthreads();
    float acc[16];
    #pragma unroll
    for (int e = 0; e < 16; ++e) acc[e] = 0.0f;
    #pragma unroll
    for (int ii = 0; ii < 2; ++ii) {
        const int il = chunk * 2 + ii;
        const int i  = i0 + il;
        float f[16];
        const float4* fp = (const float4*)(F_in + (b * 64 + i) * 16);
        #pragma unroll
        for (int v = 0; v < 4; ++v) {
            float4 x = fp[v];
            f[v*4+0]=x.x; f[v*4+1]=x.y; f[v*4+2]=x.z; f[v*4+3]=x.w;
        }
        const float* wb  = smem + il * 16;
        const float* wbb = smem + 128  + il * 16;
        const float* wc  = smem + 256  + il * 256;
        const float* wsn = smem + 2304 + il * 256;
        const float* wbc = smem + 4352 + il * 256;
        const float* wbs = smem + 6400 + il * 256;
        float U[16], Ub[16];
        #pragma unroll
        for (int e = 0; e < 16; ++e) { U[e] = wb[e]; Ub[e] = wbb[e]; }
        #pragma unroll 4
        for (int c = 0; c < 16; ++c) {
            const float cc = csc[c], ss = css[c];
            #pragma unroll
            for (int e = 0; e < 16; ++e) {
                U[e]  = fmaf(wc [c*16+e], cc, U[e]);
                U[e]  = fmaf(wsn[c*16+e], ss, U[e]);
                Ub[e] = fmaf(wbc[c*16+e], cc, Ub[e]);
                Ub[e] = fmaf(wbs[c*16+e], ss, Ub[e]);
            }
        }
        #pragma unroll
        for (int p = 0; p < 4; ++p)
            #pragma unroll
            for (int r = 0; r < 4; ++r) {
                float a = acc[p*4+r];
                #pragma unroll
                for (int q = 0; q < 4; ++q) {
                    a = fmaf(f[p*4+q],  U[q*4+r], a);
                    a = fmaf(Ub[p*4+q], f[q*4+r], a);
                }
                acc[p*4+r] = a;
            }
    }
    __syncthreads();
    if (chunk > 0) {
        float* r = smem + (chunk - 1) * 1088 + lane * 17;
        #pragma unroll
        for (int e = 0; e < 16; ++e) r[e] = acc[e];
    }
    __syncthreads();
    if (chunk == 0) {
        #pragma unroll
        for (int cc = 0; cc < 3; ++cc) {
            const float* r = smem + cc * 1088 + lane * 17;
            #pragma unroll
            for (int e = 0; e < 16; ++e) acc[e] += r[e];
        }
        float* o = out + ((size_t)b * 64 + j) * 16;
        #pragma unroll
        for (int e = 0; e < 16; ++e) atomicAdd(o + e, acc[e]);
    }
}

extern "C" void kernel_launch(void* const* d_in, const int* in_sizes, int n_in,
                              void* d_out, int out_size, void* d_ws, size_t ws_size,
                              hipStream_t stream) {
    const float* F_in    = (const float*)d_in[0];
    const float* theta   = (const float*)d_in[1];
    const float* W_bias  = (const float*)d_in[2];
    const float* W_cos   = (const float*)d_in[3];
    const float* W_sin   = (const float*)d_in[4];
    const float* Wb_bias = (const float*)d_in[5];
    const float* Wb_cos  = (const float*)d_in[6];
    const float* Wb_sin  = (const float*)d_in[7];
    float* out = (float*)d_out;

    hipMemsetAsync(out, 0, (size_t)out_size * sizeof(float), stream);

    const size_t needA = 2 * A_ELems * sizeof(short);   // 69.2 MB
    const size_t needB = 2 * B_ELems * sizeof(short);   // 8.65 MB
    if (ws_size >= needA + needB) {
        short* Abuf = (short*)d_ws;
        short* Bbuf = (short*)((char*)d_ws + needA);
        nro_prep_a<<<256, 256, 0, stream>>>(F_in, theta, Abuf);
        nro_prep_b<<<256, 256, 0, stream>>>(W_bias, W_cos, W_sin,
                                            Wb_bias, Wb_cos, Wb_sin, Bbuf);
        nro_gemm<<<dim3(32, 8, 2), 256, 0, stream>>>(Abuf, Bbuf, out);
    } else {
        dim3 grid(64 * 8, 512 / 64, 1);
        nro_fallback<<<grid, 256, 0, stream>>>(
            F_in, theta, W_bias, W_cos, W_sin, Wb_bias, Wb_cos, Wb_sin, out);
    }
}

// Round 6
// 124.821 us; speedup vs baseline: 1.7349x; 1.7349x over previous
//
#include <hip/hip_runtime.h>

// NeuralRodriguesOperator: B=512, C_L=64, C_J=16, 4x4 matrices.
// R6: same verified bf16-GEMM reformulation as R5 (passed, absmax 0.0039):
//   trig[b,c'] = (1, cos th, sin th),  k = c'*256 + i*4 + q, K=8448
//   A1[(b,p),k] = trig*F[b,i,p,q]   B1t[(j,r),k] = Wcat [j,i,c',q,r]
//   A2[(b,r),k] = trig*F[b,i,q,r]   B2t[(j,p),k] = Wbcat[j,i,c',p,q]
//   out[b,j,p,r] = C1[(b,p),(j,r)] + C2[(b,r),(j,p)]
// R5 lessons (counters): 33.5M fp32 atomics (WRITE 98MB) + A re-fetch +
// latency-exposed K-loop -> GEMM 127us @ MfmaUtil 5%. R6 fixes:
//  (a) split-K partials to ws (plain stores) + permuting reduce kernel
//  (b) block tile 64m x 256n (full N): A read exactly once; B k-slices
//      disjoint across (z,sk) -> FETCH ~= 87 MB, no re-reads
//  (c) preps fused into one kernel (3 launches total, no memset)

#define NRO_B   512
#define NRO_CL  64
#define NRO_CJ  16
#define K_DIM   8448          // 33 * 256
#define M_DIM   2048
#define N_DIM   256
#define SK      8             // split-K factor; 1056 = 33 chunks of 32 per split
#define A_ELems ((size_t)M_DIM * K_DIM)
#define B_ELems ((size_t)N_DIM * K_DIM)
#define P_ELems ((size_t)2 * SK * M_DIM * N_DIM)   // fp32 partials

typedef __attribute__((ext_vector_type(8))) short short8;
typedef __attribute__((ext_vector_type(4))) float floatx4;

__device__ __forceinline__ short f2bf(float x) {
    union { float f; unsigned u; } a; a.f = x;
    unsigned r = a.u + 0x7FFF + ((a.u >> 16) & 1);   // RNE
    return (short)(r >> 16);
}

__device__ __forceinline__ void load16(const float* p, float w[4][4]) {
    const float4* p4 = (const float4*)p;
    #pragma unroll
    for (int a = 0; a < 4; ++a) {
        float4 x = p4[a];
        w[a][0] = x.x; w[a][1] = x.y; w[a][2] = x.z; w[a][3] = x.w;
    }
}

// ---------------- fused prep: blocks [0,256) do A, [256,512) do B ----------------
__global__ __launch_bounds__(256) void nro_prep(
    const float* __restrict__ F_in, const float* __restrict__ theta,
    const float* __restrict__ W_bias, const float* __restrict__ W_cos,
    const float* __restrict__ W_sin,  const float* __restrict__ Wb_bias,
    const float* __restrict__ Wb_cos, const float* __restrict__ Wb_sin,
    short* __restrict__ Abuf,                 // [2][2048][8448] bf16
    short* __restrict__ Bbuf)                 // [2][256][8448] bf16
{
    if (blockIdx.x < 256) {
        // ---- prep A: one wave per (mat, b) [verified R5] ----
        const int unit = blockIdx.x * 4 + (threadIdx.x >> 6);
        const int mat  = unit >> 9;
        const int b    = unit & 511;
        const int i    = threadIdx.x & 63;

        float f[4][4];
        load16(F_in + ((size_t)b * 64 + i) * 16, f);

        float tc[33];
        tc[0] = 1.0f;
        #pragma unroll
        for (int c = 0; c < 16; ++c) {
            float th = theta[b * 16 + c];
            tc[1 + c]  = __cosf(th);
            tc[17 + c] = __sinf(th);
        }

        float rv[4][4];
        #pragma unroll
        for (int a = 0; a < 4; ++a)
            #pragma unroll
            for (int q = 0; q < 4; ++q)
                rv[a][q] = (mat == 0) ? f[a][q] : f[q][a];

        #pragma unroll
        for (int a = 0; a < 4; ++a) {
            short* rowp = Abuf + ((size_t)mat * M_DIM + b * 4 + a) * K_DIM + i * 4;
            #pragma unroll
            for (int cp = 0; cp < 33; ++cp) {
                float t = tc[cp];
                short4 v;
                v.x = f2bf(rv[a][0] * t); v.y = f2bf(rv[a][1] * t);
                v.z = f2bf(rv[a][2] * t); v.w = f2bf(rv[a][3] * t);
                *(short4*)(rowp + cp * 256) = v;
            }
        }
    } else {
        // ---- prep B: one wave per (j, c) [verified R5] ----
        const int unit = (blockIdx.x - 256) * 4 + (threadIdx.x >> 6);
        const int j = unit >> 4;
        const int c = unit & 15;
        const int i = threadIdx.x & 63;

        short* B1 = Bbuf;
        short* B2 = Bbuf + B_ELems;

        const size_t wbase = (((size_t)(j * 64 + i)) * 16 + c) * 16;
        float wc[4][4], ws[4][4], wbc[4][4], wbs[4][4];
        load16(W_cos  + wbase, wc);
        load16(W_sin  + wbase, ws);
        load16(Wb_cos + wbase, wbc);
        load16(Wb_sin + wbase, wbs);

        #pragma unroll
        for (int r = 0; r < 4; ++r) {
            short* n1 = B1 + (size_t)(j * 4 + r) * K_DIM + i * 4;
            short4 v;
            v.x = f2bf(wc[0][r]); v.y = f2bf(wc[1][r]); v.z = f2bf(wc[2][r]); v.w = f2bf(wc[3][r]);
            *(short4*)(n1 + (1 + c) * 256) = v;
            v.x = f2bf(ws[0][r]); v.y = f2bf(ws[1][r]); v.z = f2bf(ws[2][r]); v.w = f2bf(ws[3][r]);
            *(short4*)(n1 + (17 + c) * 256) = v;
        }
        #pragma unroll
        for (int p = 0; p < 4; ++p) {
            short* n2 = B2 + (size_t)(j * 4 + p) * K_DIM + i * 4;
            short4 v;
            v.x = f2bf(wbc[p][0]); v.y = f2bf(wbc[p][1]); v.z = f2bf(wbc[p][2]); v.w = f2bf(wbc[p][3]);
            *(short4*)(n2 + (1 + c) * 256) = v;
            v.x = f2bf(wbs[p][0]); v.y = f2bf(wbs[p][1]); v.z = f2bf(wbs[p][2]); v.w = f2bf(wbs[p][3]);
            *(short4*)(n2 + (17 + c) * 256) = v;
        }

        if (c == 0) {
            float t1[4][4], t2[4][4];
            load16(W_bias  + ((size_t)(j * 64 + i)) * 16, t1);
            load16(Wb_bias + ((size_t)(j * 64 + i)) * 16, t2);
            #pragma unroll
            for (int r = 0; r < 4; ++r) {
                short4 v;
                v.x = f2bf(t1[0][r]); v.y = f2bf(t1[1][r]); v.z = f2bf(t1[2][r]); v.w = f2bf(t1[3][r]);
                *(short4*)(B1 + (size_t)(j * 4 + r) * K_DIM + i * 4) = v;
            }
            #pragma unroll
            for (int p = 0; p < 4; ++p) {
                short4 v;
                v.x = f2bf(t2[p][0]); v.y = f2bf(t2[p][1]); v.z = f2bf(t2[p][2]); v.w = f2bf(t2[p][3]);
                *(short4*)(B2 + (size_t)(j * 4 + p) * K_DIM + i * 4) = v;
            }
        }
    }
}

// ---------------- GEMM: 64m x 256n tile, split-K, partial stores ----------------
// grid.x = zs (16): z = zs>>3, sk = zs&7;  grid.y = m-tile (32).
// Same-(z,sk) blocks (shared B k-slice) have flat ids == zs mod 16 -> same XCD.
__global__ __launch_bounds__(256, 2) void nro_gemm(
    const short* __restrict__ Abuf, const short* __restrict__ Bbuf,
    float* __restrict__ part)                 // [2*SK][2048][256] fp32
{
    const int zs = blockIdx.x;                // 0..15
    const int z  = zs >> 3;
    const int sk = zs & 7;
    const int m0 = blockIdx.y * 64;
    const int kb = sk * (K_DIM / SK);         // 1056

    const short* A  = Abuf + (size_t)z * A_ELems;
    const short* Bm = Bbuf + (size_t)z * B_ELems;

    __shared__ short As[64 * 32];             // 4 KB
    __shared__ short Bs[256 * 32];            // 16 KB

    const int tid  = threadIdx.x;
    const int lane = tid & 63;
    const int w    = tid >> 6;                // wave 0..3
    const int wn   = w * 64;                  // wave's n-range

    floatx4 acc[4][4] = {};

    const int rsub = lane >> 2;               // 0..15 row within 16-row group
    const int col8 = (lane & 3) * 8;          // k-offset (elements)

    for (int kt = 0; kt < 33; ++kt) {
        const int k0 = kb + kt * 32;
        __syncthreads();                       // prior frags consumed
        // As: wave w stages rows [w*16, w*16+16)
        {
            const short* ga = A + (size_t)(m0 + w * 16 + rsub) * K_DIM + k0 + col8;
            __builtin_amdgcn_global_load_lds(
                (const __attribute__((address_space(1))) void*)ga,
                (__attribute__((address_space(3))) void*)(As + (w * 16) * 32),
                16, 0, 0);
        }
        // Bs: wave w stages its own n-range rows [w*64, w*64+64)
        #pragma unroll
        for (int r = 0; r < 4; ++r) {
            const short* gb = Bm + (size_t)(wn + r * 16 + rsub) * K_DIM + k0 + col8;
            __builtin_amdgcn_global_load_lds(
                (const __attribute__((address_space(1))) void*)gb,
                (__attribute__((address_space(3))) void*)(Bs + (wn + r * 16) * 32),
                16, 0, 0);
        }
        __syncthreads();                       // vmcnt(0) drain + barrier

        const int fr = lane & 15;
        const int fq = (lane >> 4) * 8;
        short8 af[4], bf[4];
        #pragma unroll
        for (int t = 0; t < 4; ++t) {
            af[t] = *(const short8*)(As + (t * 16 + fr) * 32 + fq);
            bf[t] = *(const short8*)(Bs + (wn + t * 16 + fr) * 32 + fq);
        }
        #pragma unroll
        for (int mt = 0; mt < 4; ++mt)
            #pragma unroll
            for (int nt = 0; nt < 4; ++nt)
                acc[mt][nt] = __builtin_amdgcn_mfma_f32_16x16x32_bf16(
                    af[mt], bf[nt], acc[mt][nt], 0, 0, 0);
    }

    // Plain partial stores: C row m=(lane>>4)*4+e, col n=lane&15 [verified].
    const int col  = lane & 15;
    const int row4 = (lane >> 4) * 4;
    #pragma unroll
    for (int mt = 0; mt < 4; ++mt) {
        #pragma unroll
        for (int nt = 0; nt < 4; ++nt) {
            #pragma unroll
            for (int e = 0; e < 4; ++e) {
                const int m = m0 + mt * 16 + row4 + e;
                const int n = wn + nt * 16 + col;
                part[((size_t)zs * M_DIM + m) * N_DIM + n] = acc[mt][nt][e];
            }
        }
    }
}

// ---------------- reduce: sum 16 partials, apply permutation ----------------
// t = b*256 + j*4 + p  ->  out[b,j,p,0..3] as float4 (coalesced stores)
__global__ __launch_bounds__(256) void nro_reduce(
    const float* __restrict__ part, float* __restrict__ out)
{
    const int t = blockIdx.x * 256 + threadIdx.x;   // 131072
    const int b = t >> 8;
    const int j = (t >> 2) & 63;
    const int p = t & 3;

    float4 o = make_float4(0.f, 0.f, 0.f, 0.f);
    #pragma unroll
    for (int sk = 0; sk < SK; ++sk) {
        // C1[(b,p)][(j,r)] : contiguous float4 over r
        const float4 c1 = *(const float4*)(
            part + ((size_t)sk * M_DIM + b * 4 + p) * N_DIM + j * 4);
        o.x += c1.x; o.y += c1.y; o.z += c1.z; o.w += c1.w;
        // C2[(b,r)][(j,p)] : r varies over rows
        const float* p2 = part + ((size_t)(SK + sk) * M_DIM + b * 4) * N_DIM + j * 4 + p;
        o.x += p2[0 * N_DIM]; o.y += p2[1 * N_DIM];
        o.z += p2[2 * N_DIM]; o.w += p2[3 * N_DIM];
    }
    *(float4*)(out + ((size_t)(b * 64 + j) * 16 + p * 4)) = o;
}

// ---------------- fallback (R4 fp32 path, atomic epilogue) ----------------
__global__ __launch_bounds__(256, 2) void nro_fallback(
    const float* __restrict__ F_in, const float* __restrict__ theta,
    const float* __restrict__ W_bias, const float* __restrict__ W_cos,
    const float* __restrict__ W_sin,  const float* __restrict__ Wb_bias,
    const float* __restrict__ Wb_cos, const float* __restrict__ Wb_sin,
    float* __restrict__ out)
{
    __shared__ float smem[8448];
    const int j      = blockIdx.x >> 3;
    const int isplit = blockIdx.x & 7;
    const int i0     = isplit * 8;
    const int lane   = threadIdx.x & 63;
    const int chunk  = __builtin_amdgcn_readfirstlane(threadIdx.x >> 6);
    const int b      = blockIdx.y * 64 + lane;
    const int tid    = threadIdx.x;
    {
        float4* s4 = (float4*)smem;
        const int base16  = (j * 64 + i0) * 16;
        const int base256 = (j * 64 + i0) * 256;
        if (tid < 32)      s4[tid] = ((const float4*)(W_bias + base16))[tid];
        else if (tid < 64) s4[tid] = ((const float4*)(Wb_bias + base16))[tid - 32];
        #pragma unroll
        for (int r = 0; r < 2; ++r) {
            const int k = r * 256 + tid;
            s4[64 + k]   = ((const float4*)(W_cos  + base256))[k];
            s4[576 + k]  = ((const float4*)(W_sin  + base256))[k];
            s4[1088 + k] = ((const float4*)(Wb_cos + base256))[k];
            s4[1600 + k] = ((const float4*)(Wb_sin + base256))[k];
        }
    }
    float csc[16], css[16];
    #pragma unroll
    for (int c = 0; c < 16; ++c) {
        float t = theta[b * 16 + c];
        csc[c] = __cosf(t); css[c] = __sinf(t);
    }
    __syncthreads();
    float acc[16];
    #pragma unroll
    for (int e = 0; e < 16; ++e) acc[e] = 0.0f;
    #pragma unroll
    for (int ii = 0; ii < 2; ++ii) {
        const int il = chunk * 2 + ii;
        const int i  = i0 + il;
        float f[16];
        const float4* fp = (const float4*)(F_in + (b * 64 + i) * 16);
        #pragma unroll
        for (int v = 0; v < 4; ++v) {
            float4 x = fp[v];
            f[v*4+0]=x.x; f[v*4+1]=x.y; f[v*4+2]=x.z; f[v*4+3]=x.w;
        }
        const float* wb  = smem + il * 16;
        const float* wbb = smem + 128  + il * 16;
        const float* wc  = smem + 256  + il * 256;
        const float* wsn = smem + 2304 + il * 256;
        const float* wbc = smem + 4352 + il * 256;
        const float* wbs = smem + 6400 + il * 256;
        float U[16], Ub[16];
        #pragma unroll
        for (int e = 0; e < 16; ++e) { U[e] = wb[e]; Ub[e] = wbb[e]; }
        #pragma unroll 4
        for (int c = 0; c < 16; ++c) {
            const float cc = csc[c], ss = css[c];
            #pragma unroll
            for (int e = 0; e < 16; ++e) {
                U[e]  = fmaf(wc [c*16+e], cc, U[e]);
                U[e]  = fmaf(wsn[c*16+e], ss, U[e]);
                Ub[e] = fmaf(wbc[c*16+e], cc, Ub[e]);
                Ub[e] = fmaf(wbs[c*16+e], ss, Ub[e]);
            }
        }
        #pragma unroll
        for (int p = 0; p < 4; ++p)
            #pragma unroll
            for (int r = 0; r < 4; ++r) {
                float a = acc[p*4+r];
                #pragma unroll
                for (int q = 0; q < 4; ++q) {
                    a = fmaf(f[p*4+q],  U[q*4+r], a);
                    a = fmaf(Ub[p*4+q], f[q*4+r], a);
                }
                acc[p*4+r] = a;
            }
    }
    __syncthreads();
    if (chunk > 0) {
        float* r = smem + (chunk - 1) * 1088 + lane * 17;
        #pragma unroll
        for (int e = 0; e < 16; ++e) r[e] = acc[e];
    }
    __syncthreads();
    if (chunk == 0) {
        #pragma unroll
        for (int cc = 0; cc < 3; ++cc) {
            const float* r = smem + cc * 1088 + lane * 17;
            #pragma unroll
            for (int e = 0; e < 16; ++e) acc[e] += r[e];
        }
        float* o = out + ((size_t)b * 64 + j) * 16;
        #pragma unroll
        for (int e = 0; e < 16; ++e) atomicAdd(o + e, acc[e]);
    }
}

extern "C" void kernel_launch(void* const* d_in, const int* in_sizes, int n_in,
                              void* d_out, int out_size, void* d_ws, size_t ws_size,
                              hipStream_t stream) {
    const float* F_in    = (const float*)d_in[0];
    const float* theta   = (const float*)d_in[1];
    const float* W_bias  = (const float*)d_in[2];
    const float* W_cos   = (const float*)d_in[3];
    const float* W_sin   = (const float*)d_in[4];
    const float* Wb_bias = (const float*)d_in[5];
    const float* Wb_cos  = (const float*)d_in[6];
    const float* Wb_sin  = (const float*)d_in[7];
    float* out = (float*)d_out;

    const size_t needA = 2 * A_ELems * sizeof(short);   // 69.2 MB
    const size_t needB = 2 * B_ELems * sizeof(short);   // 8.65 MB
    const size_t needP = P_ELems * sizeof(float);       // 33.55 MB
    if (ws_size >= needA + needB + needP) {
        short* Abuf = (short*)d_ws;
        short* Bbuf = (short*)((char*)d_ws + needA);
        float* part = (float*)((char*)d_ws + needA + needB);
        nro_prep<<<512, 256, 0, stream>>>(F_in, theta, W_bias, W_cos, W_sin,
                                          Wb_bias, Wb_cos, Wb_sin, Abuf, Bbuf);
        nro_gemm<<<dim3(16, 32), 256, 0, stream>>>(Abuf, Bbuf, part);
        nro_reduce<<<512, 256, 0, stream>>>(part, out);
    } else {
        hipMemsetAsync(out, 0, (size_t)out_size * sizeof(float), stream);
        dim3 grid(64 * 8, 512 / 64, 1);
        nro_fallback<<<grid, 256, 0, stream>>>(
            F_in, theta, W_bias, W_cos, W_sin, Wb_bias, Wb_cos, Wb_sin, out);
    }
}

// Round 7
// 115.027 us; speedup vs baseline: 1.8826x; 1.0851x over previous
//
#include <hip/hip_runtime.h>

// NeuralRodriguesOperator: B=512, C_L=64, C_J=16, 4x4 matrices.
// R7: A-matrix never materialized. A[(b,a),(c',iq)] = trig[b,c']*Fv[(b,a),iq]
// is rank-1 in c'; each 32-wide k-chunk sits inside one c' block, so the GEMM
// synthesizes A-fragments in-register: Fv fragment (LDS) x per-lane scalar
// trig[b,c'] via v_pk_mul_f16 (hence fp16, not bf16 — no packed bf16 mul;
// f16 MFMA rate identical, precision better). Kills 69 MB prep-A write +
// 69 MB GEMM A-read (R6 prep was 44.5 us, the top dispatch).
//   trig[b,c'] = (1, cos th, sin th), k = c'*256 + i*4 + q, K=8448
//   C1[(b,p),(j,r)]: Fv0*trig vs B1t = Wcat[j,i,c',q,r]
//   C2[(b,r),(j,p)]: Fv1*trig vs B2t = Wbcat[j,i,c',p,q]
//   out[b,j,p,r] = C1 + C2   (reduce kernel, verified R6)
// Fs LDS rows padded 256->264 halfs: unpadded 512B stride = 16-way bank
// conflict on ds_read_b128; padded ~2-way (free). Bs keeps the m97 layout
// (global_load_lds needs contiguity; ~8-way tolerated per m97/R5 evidence).

#define NRO_B   512
#define NRO_CL  64
#define K_DIM   8448          // 33 * 256
#define M_DIM   2048
#define N_DIM   256
#define SK      8
#define B_ELems  ((size_t)N_DIM * K_DIM)       // per matrix (fp16)
#define FV_ELems ((size_t)M_DIM * N_DIM)       // per matrix (fp16)
#define P_ELems  ((size_t)2 * SK * M_DIM * N_DIM)  // fp32 partials

typedef __attribute__((ext_vector_type(8))) _Float16 half8;
typedef __attribute__((ext_vector_type(4))) _Float16 half4_t;
typedef __attribute__((ext_vector_type(4))) float floatx4;

__device__ __forceinline__ void load16(const float* p, float w[4][4]) {
    const float4* p4 = (const float4*)p;
    #pragma unroll
    for (int a = 0; a < 4; ++a) {
        float4 x = p4[a];
        w[a][0] = x.x; w[a][1] = x.y; w[a][2] = x.z; w[a][3] = x.w;
    }
}

__device__ __forceinline__ half8 scale8(half8 v, _Float16 s) {
    half8 r;
    #pragma unroll
    for (int x = 0; x < 8; ++x) r[x] = v[x] * s;   // -> v_pk_mul_f16 x4
    return r;
}

// ---------------- prep: blocks [0,128) Fv, [128,640) B ----------------
__global__ __launch_bounds__(256) void nro_prep(
    const float* __restrict__ F_in,
    const float* __restrict__ W_bias, const float* __restrict__ W_cos,
    const float* __restrict__ W_sin,  const float* __restrict__ Wb_bias,
    const float* __restrict__ Wb_cos, const float* __restrict__ Wb_sin,
    _Float16* __restrict__ Bbuf,              // [2][256][8448]
    _Float16* __restrict__ Fv)                // [2][2048][256]
{
    const int w = threadIdx.x >> 6, i = threadIdx.x & 63;
    if (blockIdx.x < 128) {
        // Fv0[(b,p)][(i,q)] = F[b,i,p,q];  Fv1[(b,r)][(i,q)] = F[b,i,q,r]
        const int b = blockIdx.x * 4 + w;     // 0..511
        float f[4][4];
        load16(F_in + ((size_t)b * 64 + i) * 16, f);
        #pragma unroll
        for (int a = 0; a < 4; ++a) {
            half4_t v0 = { (_Float16)f[a][0], (_Float16)f[a][1],
                           (_Float16)f[a][2], (_Float16)f[a][3] };
            *(half4_t*)(Fv + (size_t)(b * 4 + a) * 256 + i * 4) = v0;
            half4_t v1 = { (_Float16)f[0][a], (_Float16)f[1][a],
                           (_Float16)f[2][a], (_Float16)f[3][a] };
            *(half4_t*)(Fv + FV_ELems + (size_t)(b * 4 + a) * 256 + i * 4) = v1;
        }
    } else {
        // one wave per (j, c, h): h=0 -> B1 (transposed q<->r), h=1 -> B2
        const int unit = (blockIdx.x - 128) * 4 + w;   // 0..2047
        const int j = unit >> 5, c = (unit >> 1) & 15, h = unit & 1;
        _Float16* Bd = Bbuf + (size_t)h * B_ELems;
        const size_t wbase = (((size_t)(j * 64 + i)) * 16 + c) * 16;

        float wc4[4][4], ws4[4][4];
        if (h == 0) { load16(W_cos  + wbase, wc4); load16(W_sin  + wbase, ws4); }
        else        { load16(Wb_cos + wbase, wc4); load16(Wb_sin + wbase, ws4); }

        #pragma unroll
        for (int a = 0; a < 4; ++a) {
            _Float16* n = Bd + (size_t)(j * 4 + a) * K_DIM + i * 4;
            half4_t vc, vs;
            if (h == 0) {   // B1[(j,r=a)][..q] = W[q][a]
                vc = (half4_t){ (_Float16)wc4[0][a], (_Float16)wc4[1][a],
                                (_Float16)wc4[2][a], (_Float16)wc4[3][a] };
                vs = (half4_t){ (_Float16)ws4[0][a], (_Float16)ws4[1][a],
                                (_Float16)ws4[2][a], (_Float16)ws4[3][a] };
            } else {        // B2[(j,p=a)][..q] = Wb[a][q]
                vc = (half4_t){ (_Float16)wc4[a][0], (_Float16)wc4[a][1],
                                (_Float16)wc4[a][2], (_Float16)wc4[a][3] };
                vs = (half4_t){ (_Float16)ws4[a][0], (_Float16)ws4[a][1],
                                (_Float16)ws4[a][2], (_Float16)ws4[a][3] };
            }
            *(half4_t*)(n + (1 + c)  * 256) = vc;
            *(half4_t*)(n + (17 + c) * 256) = vs;
        }
        if (c == 0) {       // c'=0 bias column block
            float t[4][4];
            load16(((h == 0) ? W_bias : Wb_bias) + ((size_t)(j * 64 + i)) * 16, t);
            #pragma unroll
            for (int a = 0; a < 4; ++a) {
                half4_t v;
                if (h == 0) v = (half4_t){ (_Float16)t[0][a], (_Float16)t[1][a],
                                           (_Float16)t[2][a], (_Float16)t[3][a] };
                else        v = (half4_t){ (_Float16)t[a][0], (_Float16)t[a][1],
                                           (_Float16)t[a][2], (_Float16)t[a][3] };
                *(half4_t*)(Bd + (size_t)(j * 4 + a) * K_DIM + i * 4) = v;
            }
        }
    }
}

// ---------------- GEMM: 64m x 256n, split-K, A synthesized in-register ----------------
// grid.x = zs (16): z=zs>>3, sk=zs&7; grid.y = m-tile (32).
// flat id = y*16+x -> id%8 = zs%8: same-B blocks share an XCD.
__global__ __launch_bounds__(256, 2) void nro_gemm(
    const _Float16* __restrict__ Bbuf, const _Float16* __restrict__ Fv,
    const float* __restrict__ theta,
    float* __restrict__ part)                 // [16][2048][256] fp32
{
    const int zs = blockIdx.x;                // 0..15
    const int z  = zs >> 3;
    const int sk = zs & 7;
    const int m0 = blockIdx.y * 64;

    const _Float16* Bm = Bbuf + (size_t)z * B_ELems;
    const _Float16* Fm = Fv + (size_t)z * FV_ELems + (size_t)m0 * 256;

    __shared__ _Float16 Fs[64 * 264];         // rows padded +8 halfs
    __shared__ _Float16 Bs[256 * 32];
    __shared__ float    trig[16 * 34];        // [b_local][c'] (c'=0 -> 1.0)

    const int tid  = threadIdx.x;
    const int lane = tid & 63;
    const int w    = tid >> 6;
    const int wn   = w * 64;

    // ---- stage Fs (VGPR round-trip: padding breaks global_load_lds) ----
    #pragma unroll
    for (int kk = 0; kk < 8; ++kk) {
        const int idx = kk * 256 + tid;       // 2048 half8-chunks
        const int row = idx >> 5, cf = idx & 31;
        half8 v = *(const half8*)(Fm + (size_t)row * 256 + cf * 8);
        *(half8*)(Fs + row * 264 + cf * 8) = v;
    }
    // ---- stage trig from theta directly ----
    {
        const int bl = tid >> 4, c = tid & 15;
        const float th = theta[(m0 >> 2) * 16 + tid];   // theta[b0+bl][c]
        trig[bl * 34 + 1 + c]  = __cosf(th);
        trig[bl * 34 + 17 + c] = __sinf(th);
        if (c == 0) trig[bl * 34] = 1.0f;
    }

    floatx4 acc[4][4] = {};
    const int rsub = lane >> 2, col8 = (lane & 3) * 8;
    const int fr = lane & 15,  fq = (lane >> 4) * 8;
    _Float16 tv[4] = {};

    for (int kt = 0; kt < 33; ++kt) {
        const int g   = sk * 33 + kt;         // global k-chunk
        const int cp  = g >> 3;               // c' (fixed within a chunk)
        const int iq0 = (g & 7) * 32;         // column in Fv
        const int k0  = g * 32;               // column in B
        __syncthreads();                       // prev Bs consumed (+Fs/trig on kt=0)
        #pragma unroll
        for (int r = 0; r < 4; ++r) {
            const _Float16* gb = Bm + (size_t)(wn + r * 16 + rsub) * K_DIM + k0 + col8;
            __builtin_amdgcn_global_load_lds(
                (const __attribute__((address_space(1))) void*)gb,
                (__attribute__((address_space(3))) void*)(Bs + (wn + r * 16) * 32),
                16, 0, 0);
        }
        if (kt == 0 || (g & 7) == 0) {        // c' changed: refresh per-lane trig
            #pragma unroll
            for (int t = 0; t < 4; ++t)
                tv[t] = (_Float16)trig[(t * 4 + (fr >> 2)) * 34 + cp];
        }
        __syncthreads();                       // Bs ready

        half8 af[4], bf[4];
        #pragma unroll
        for (int t = 0; t < 4; ++t) {
            half8 fvf = *(const half8*)(Fs + (t * 16 + fr) * 264 + iq0 + fq);
            af[t] = scale8(fvf, tv[t]);        // A = trig * Fv
            bf[t] = *(const half8*)(Bs + (wn + t * 16 + fr) * 32 + fq);
        }
        #pragma unroll
        for (int mt = 0; mt < 4; ++mt)
            #pragma unroll
            for (int nt = 0; nt < 4; ++nt)
                acc[mt][nt] = __builtin_amdgcn_mfma_f32_16x16x32_f16(
                    af[mt], bf[nt], acc[mt][nt], 0, 0, 0);
    }

    // C row m=(lane>>4)*4+e, col n=lane&15 [verified R5/R6]
    const int col = lane & 15, row4 = (lane >> 4) * 4;
    #pragma unroll
    for (int mt = 0; mt < 4; ++mt)
        #pragma unroll
        for (int nt = 0; nt < 4; ++nt)
            #pragma unroll
            for (int e = 0; e < 4; ++e) {
                const int m = m0 + mt * 16 + row4 + e;
                const int n = wn + nt * 16 + col;
                part[((size_t)zs * M_DIM + m) * N_DIM + n] = acc[mt][nt][e];
            }
}

// ---------------- reduce: sum 16 partials, apply permutation [verified R6] ----------------
__global__ __launch_bounds__(256) void nro_reduce(
    const float* __restrict__ part, float* __restrict__ out)
{
    const int t = blockIdx.x * 256 + threadIdx.x;   // 131072
    const int b = t >> 8;
    const int j = (t >> 2) & 63;
    const int p = t & 3;

    float4 o = make_float4(0.f, 0.f, 0.f, 0.f);
    #pragma unroll
    for (int sk = 0; sk < SK; ++sk) {
        const float4 c1 = *(const float4*)(
            part + ((size_t)sk * M_DIM + b * 4 + p) * N_DIM + j * 4);
        o.x += c1.x; o.y += c1.y; o.z += c1.z; o.w += c1.w;
        const float* p2 = part + ((size_t)(SK + sk) * M_DIM + b * 4) * N_DIM + j * 4 + p;
        o.x += p2[0 * N_DIM]; o.y += p2[1 * N_DIM];
        o.z += p2[2 * N_DIM]; o.w += p2[3 * N_DIM];
    }
    *(float4*)(out + ((size_t)(b * 64 + j) * 16 + p * 4)) = o;
}

// ---------------- fallback (R4 fp32 path, verified) ----------------
__global__ __launch_bounds__(256, 2) void nro_fallback(
    const float* __restrict__ F_in, const float* __restrict__ theta,
    const float* __restrict__ W_bias, const float* __restrict__ W_cos,
    const float* __restrict__ W_sin,  const float* __restrict__ Wb_bias,
    const float* __restrict__ Wb_cos, const float* __restrict__ Wb_sin,
    float* __restrict__ out)
{
    __shared__ float smem[8448];
    const int j      = blockIdx.x >> 3;
    const int isplit = blockIdx.x & 7;
    const int i0     = isplit * 8;
    const int lane   = threadIdx.x & 63;
    const int chunk  = __builtin_amdgcn_readfirstlane(threadIdx.x >> 6);
    const int b      = blockIdx.y * 64 + lane;
    const int tid    = threadIdx.x;
    {
        float4* s4 = (float4*)smem;
        const int base16  = (j * 64 + i0) * 16;
        const int base256 = (j * 64 + i0) * 256;
        if (tid < 32)      s4[tid] = ((const float4*)(W_bias + base16))[tid];
        else if (tid < 64) s4[tid] = ((const float4*)(Wb_bias + base16))[tid - 32];
        #pragma unroll
        for (int r = 0; r < 2; ++r) {
            const int k = r * 256 + tid;
            s4[64 + k]   = ((const float4*)(W_cos  + base256))[k];
            s4[576 + k]  = ((const float4*)(W_sin  + base256))[k];
            s4[1088 + k] = ((const float4*)(Wb_cos + base256))[k];
            s4[1600 + k] = ((const float4*)(Wb_sin + base256))[k];
        }
    }
    float csc[16], css[16];
    #pragma unroll
    for (int c = 0; c < 16; ++c) {
        float t = theta[b * 16 + c];
        csc[c] = __cosf(t); css[c] = __sinf(t);
    }
    __syncthreads();
    float acc[16];
    #pragma unroll
    for (int e = 0; e < 16; ++e) acc[e] = 0.0f;
    #pragma unroll
    for (int ii = 0; ii < 2; ++ii) {
        const int il = chunk * 2 + ii;
        const int i  = i0 + il;
        float f[16];
        const float4* fp = (const float4*)(F_in + (b * 64 + i) * 16);
        #pragma unroll
        for (int v = 0; v < 4; ++v) {
            float4 x = fp[v];
            f[v*4+0]=x.x; f[v*4+1]=x.y; f[v*4+2]=x.z; f[v*4+3]=x.w;
        }
        const float* wb  = smem + il * 16;
        const float* wbb = smem + 128  + il * 16;
        const float* wc  = smem + 256  + il * 256;
        const float* wsn = smem + 2304 + il * 256;
        const float* wbc = smem + 4352 + il * 256;
        const float* wbs = smem + 6400 + il * 256;
        float U[16], Ub[16];
        #pragma unroll
        for (int e = 0; e < 16; ++e) { U[e] = wb[e]; Ub[e] = wbb[e]; }
        #pragma unroll 4
        for (int c = 0; c < 16; ++c) {
            const float cc = csc[c], ss = css[c];
            #pragma unroll
            for (int e = 0; e < 16; ++e) {
                U[e]  = fmaf(wc [c*16+e], cc, U[e]);
                U[e]  = fmaf(wsn[c*16+e], ss, U[e]);
                Ub[e] = fmaf(wbc[c*16+e], cc, Ub[e]);
                Ub[e] = fmaf(wbs[c*16+e], ss, Ub[e]);
            }
        }
        #pragma unroll
        for (int p = 0; p < 4; ++p)
            #pragma unroll
            for (int r = 0; r < 4; ++r) {
                float a = acc[p*4+r];
                #pragma unroll
                for (int q = 0; q < 4; ++q) {
                    a = fmaf(f[p*4+q],  U[q*4+r], a);
                    a = fmaf(Ub[p*4+q], f[q*4+r], a);
                }
                acc[p*4+r] = a;
            }
    }
    __syncthreads();
    if (chunk > 0) {
        float* r = smem + (chunk - 1) * 1088 + lane * 17;
        #pragma unroll
        for (int e = 0; e < 16; ++e) r[e] = acc[e];
    }
    __syncthreads();
    if (chunk == 0) {
        #pragma unroll
        for (int cc = 0; cc < 3; ++cc) {
            const float* r = smem + cc * 1088 + lane * 17;
            #pragma unroll
            for (int e = 0; e < 16; ++e) acc[e] += r[e];
        }
        float* o = out + ((size_t)b * 64 + j) * 16;
        #pragma unroll
        for (int e = 0; e < 16; ++e) atomicAdd(o + e, acc[e]);
    }
}

extern "C" void kernel_launch(void* const* d_in, const int* in_sizes, int n_in,
                              void* d_out, int out_size, void* d_ws, size_t ws_size,
                              hipStream_t stream) {
    const float* F_in    = (const float*)d_in[0];
    const float* theta   = (const float*)d_in[1];
    const float* W_bias  = (const float*)d_in[2];
    const float* W_cos   = (const float*)d_in[3];
    const float* W_sin   = (const float*)d_in[4];
    const float* Wb_bias = (const float*)d_in[5];
    const float* Wb_cos  = (const float*)d_in[6];
    const float* Wb_sin  = (const float*)d_in[7];
    float* out = (float*)d_out;

    const size_t needB  = 2 * B_ELems  * sizeof(_Float16);  // 8.65 MB
    const size_t needFv = 2 * FV_ELems * sizeof(_Float16);  // 2.10 MB
    const size_t needP  = P_ELems * sizeof(float);          // 33.55 MB
    if (ws_size >= needB + needFv + needP) {
        _Float16* Bbuf = (_Float16*)d_ws;
        _Float16* Fv   = (_Float16*)((char*)d_ws + needB);
        float*    part = (float*)((char*)d_ws + needB + needFv);
        nro_prep<<<640, 256, 0, stream>>>(F_in, W_bias, W_cos, W_sin,
                                          Wb_bias, Wb_cos, Wb_sin, Bbuf, Fv);
        nro_gemm<<<dim3(16, 32), 256, 0, stream>>>(Bbuf, Fv, theta, part);
        nro_reduce<<<512, 256, 0, stream>>>(part, out);
    } else {
        hipMemsetAsync(out, 0, (size_t)out_size * sizeof(float), stream);
        dim3 grid(64 * 8, 512 / 64, 1);
        nro_fallback<<<grid, 256, 0, stream>>>(
            F_in, theta, W_bias, W_cos, W_sin, Wb_bias, Wb_cos, Wb_sin, out);
    }
}